// Round 1
// baseline (4497.862 us; speedup 1.0000x reference)
//
#include <hip/hip_runtime.h>

// Layout of d_out (all float32):
//   [0,           N*D)      mean_messages  (accumulated as sums, then divided)
//   [N*D,         N*D+N)    last_timestamps
//   [N*D+N,       N*D+2N)   counts
//
// Scatter phase: 64 threads per event, float4 per thread (D=256).
// Timestamps are sorted ascending => last timestamp per node == max timestamp
// per node; max over non-negative floats == integer max on the bit pattern.

__global__ void scatter_kernel(const int* __restrict__ node_ids,
                               const float* __restrict__ messages,
                               const float* __restrict__ timestamps,
                               float* __restrict__ sums,     // [N, D]
                               float* __restrict__ last_ts,  // [N]
                               float* __restrict__ counts,   // [N]
                               int B, int D) {
    int t = blockIdx.x * blockDim.x + threadIdx.x;
    int e = t >> 6;          // 64 threads per event
    int lane = t & 63;
    if (e >= B) return;

    int node = node_ids[e];
    const float4 m = *reinterpret_cast<const float4*>(
        messages + (size_t)e * D + lane * 4);
    float* dst = sums + (size_t)node * D + lane * 4;
    atomicAdd(dst + 0, m.x);
    atomicAdd(dst + 1, m.y);
    atomicAdd(dst + 2, m.z);
    atomicAdd(dst + 3, m.w);

    if (lane == 0) {
        atomicAdd(counts + node, 1.0f);
        // timestamps >= 0 => int-bit max == float max
        atomicMax(reinterpret_cast<int*>(last_ts) + node,
                  __float_as_int(timestamps[e]));
    }
}

__global__ void finalize_kernel(float* __restrict__ sums,
                                const float* __restrict__ counts,
                                int N, int D) {
    int t = blockIdx.x * blockDim.x + threadIdx.x;
    int n = t >> 6;          // 64 threads per node row
    int lane = t & 63;
    if (n >= N) return;

    float c = counts[n];
    float inv = 1.0f / fmaxf(c, 1.0f);
    float4* p = reinterpret_cast<float4*>(sums + (size_t)n * D + lane * 4);
    float4 v = *p;
    v.x *= inv; v.y *= inv; v.z *= inv; v.w *= inv;
    *p = v;
}

extern "C" void kernel_launch(void* const* d_in, const int* in_sizes, int n_in,
                              void* d_out, int out_size, void* d_ws, size_t ws_size,
                              hipStream_t stream) {
    const int*   node_ids   = (const int*)  d_in[0];
    const float* messages   = (const float*)d_in[1];
    const float* timestamps = (const float*)d_in[2];
    // d_in[3] is n_nodes (device scalar) — N derived from out_size instead.

    const int B = in_sizes[0];
    const int D = in_sizes[1] / B;          // 256
    const int N = out_size / (D + 2);       // out = N*D + N + N floats

    float* out     = (float*)d_out;
    float* sums    = out;                    // [N, D]
    float* last_ts = out + (size_t)N * D;    // [N]
    float* counts  = last_ts + N;            // [N]

    // Zero the whole output (harness poisons it to 0xAA before every launch).
    hipMemsetAsync(d_out, 0, (size_t)out_size * sizeof(float), stream);

    // Scatter: 64 threads per event, 256 threads/block -> 4 events per block.
    {
        long long total_threads = (long long)B * 64;
        int block = 256;
        int grid = (int)((total_threads + block - 1) / block);
        scatter_kernel<<<grid, block, 0, stream>>>(
            node_ids, messages, timestamps, sums, last_ts, counts, B, D);
    }

    // Finalize: divide sums by counts.
    {
        long long total_threads = (long long)N * 64;
        int block = 256;
        int grid = (int)((total_threads + block - 1) / block);
        finalize_kernel<<<grid, block, 0, stream>>>(sums, counts, N, D);
    }
}

// Round 2
// 1469.927 us; speedup vs baseline: 3.0599x; 3.0599x over previous
//
#include <hip/hip_runtime.h>

// CSR-gather design (no float atomics):
//   1. count_kernel:  cnt[n] = #events per node          (int atomics, 400 KB)
//   2. scan (3 kernels): offsets = exclusive_scan(cnt)   (two-level LDS scan)
//   3. bucket_kernel: perm[offsets[n] + k] = event idx   (int atomics on cursor)
//   4. gather_kernel: one wave per node sums its rows, divides, stores.
//
// d_out layout (float32): [N*D mean | N last_ts | N counts]
// Timestamps sorted ascending => last ts per node = timestamps[max event idx].
// Every output element is written by gather_kernel => no d_out memset needed.

#define SCAN_BLOCK 256
#define L2_BLOCK   512   // single-block second-level scan capacity

__global__ void count_kernel(const int* __restrict__ node_ids,
                             int* __restrict__ cnt, int B) {
    int e = blockIdx.x * blockDim.x + threadIdx.x;
    if (e < B) atomicAdd(&cnt[node_ids[e]], 1);
}

// Per-block exclusive scan of cnt -> excl, block totals -> blockSums.
__global__ void scan_blocks(const int* __restrict__ cnt,
                            int* __restrict__ excl,
                            int* __restrict__ blockSums, int N) {
    __shared__ int s[SCAN_BLOCK];
    int gid = blockIdx.x * SCAN_BLOCK + threadIdx.x;
    int v = (gid < N) ? cnt[gid] : 0;
    s[threadIdx.x] = v;
    __syncthreads();
    for (int off = 1; off < SCAN_BLOCK; off <<= 1) {
        int t = (threadIdx.x >= off) ? s[threadIdx.x - off] : 0;
        __syncthreads();
        s[threadIdx.x] += t;
        __syncthreads();
    }
    int incl = s[threadIdx.x];
    if (gid < N) excl[gid] = incl - v;
    if (threadIdx.x == SCAN_BLOCK - 1) blockSums[blockIdx.x] = incl;
}

// Single-block exclusive scan of blockSums (nb <= L2_BLOCK).
__global__ void scan_block_sums(int* __restrict__ blockSums, int nb) {
    __shared__ int s[L2_BLOCK];
    int v = (threadIdx.x < nb) ? blockSums[threadIdx.x] : 0;
    s[threadIdx.x] = v;
    __syncthreads();
    for (int off = 1; off < L2_BLOCK; off <<= 1) {
        int t = (threadIdx.x >= off) ? s[threadIdx.x - off] : 0;
        __syncthreads();
        s[threadIdx.x] += t;
        __syncthreads();
    }
    if (threadIdx.x < nb) blockSums[threadIdx.x] = s[threadIdx.x] - v;
}

// excl += blockSums[block]; cursor = excl (mutable copy for bucketing).
__global__ void add_offsets(int* __restrict__ excl,
                            const int* __restrict__ blockSums,
                            int* __restrict__ cursor, int N) {
    int gid = blockIdx.x * SCAN_BLOCK + threadIdx.x;
    if (gid < N) {
        int o = excl[gid] + blockSums[blockIdx.x];
        excl[gid] = o;
        cursor[gid] = o;
    }
}

__global__ void bucket_kernel(const int* __restrict__ node_ids,
                              int* __restrict__ cursor,
                              int* __restrict__ perm, int B) {
    int e = blockIdx.x * blockDim.x + threadIdx.x;
    if (e < B) {
        int pos = atomicAdd(&cursor[node_ids[e]], 1);
        perm[pos] = e;
    }
}

// One 64-lane wave per node. Lane l owns columns [4l, 4l+4).
__global__ void gather_kernel(const int* __restrict__ perm,
                              const int* __restrict__ offsets,
                              const int* __restrict__ cnt,
                              const float* __restrict__ messages,
                              const float* __restrict__ timestamps,
                              float* __restrict__ mean,     // [N, D]
                              float* __restrict__ last_ts,  // [N]
                              float* __restrict__ counts,   // [N]
                              int N, int D) {
    int wave = (blockIdx.x * blockDim.x + threadIdx.x) >> 6;
    int lane = threadIdx.x & 63;
    if (wave >= N) return;

    int start = offsets[wave];
    int c = cnt[wave];

    float4 acc = make_float4(0.f, 0.f, 0.f, 0.f);
    int last_e = -1;
    for (int i = 0; i < c; i++) {
        int e = perm[start + i];               // wave-uniform broadcast load
        const float4 m = *reinterpret_cast<const float4*>(
            messages + (size_t)e * D + lane * 4);
        acc.x += m.x; acc.y += m.y; acc.z += m.z; acc.w += m.w;
        last_e = max(last_e, e);
    }
    float inv = 1.0f / fmaxf((float)c, 1.0f);
    acc.x *= inv; acc.y *= inv; acc.z *= inv; acc.w *= inv;
    *reinterpret_cast<float4*>(mean + (size_t)wave * D + lane * 4) = acc;

    if (lane == 0) {
        counts[wave] = (float)c;
        last_ts[wave] = (c > 0) ? timestamps[last_e] : 0.0f;
    }
}

extern "C" void kernel_launch(void* const* d_in, const int* in_sizes, int n_in,
                              void* d_out, int out_size, void* d_ws, size_t ws_size,
                              hipStream_t stream) {
    const int*   node_ids   = (const int*)  d_in[0];
    const float* messages   = (const float*)d_in[1];
    const float* timestamps = (const float*)d_in[2];

    const int B = in_sizes[0];
    const int D = in_sizes[1] / B;          // 256
    const int N = out_size / (D + 2);       // out = N*D + N + N floats

    float* out     = (float*)d_out;
    float* mean    = out;                    // [N, D]
    float* last_ts = out + (size_t)N * D;    // [N]
    float* counts  = last_ts + N;            // [N]

    // Workspace layout (ints): cnt[N] | excl[N] | cursor[N] | blockSums[nb] | perm[B]
    const int nb = (N + SCAN_BLOCK - 1) / SCAN_BLOCK;   // 391 for N=100K
    int* cnt       = (int*)d_ws;
    int* excl      = cnt + N;
    int* cursor    = excl + N;
    int* blockSums = cursor + N;
    int* perm      = blockSums + nb;

    // Only cnt needs zero-init (ws is poisoned to 0xAA each launch).
    hipMemsetAsync(cnt, 0, (size_t)N * sizeof(int), stream);

    int gridB = (B + 255) / 256;
    count_kernel<<<gridB, 256, 0, stream>>>(node_ids, cnt, B);

    scan_blocks<<<nb, SCAN_BLOCK, 0, stream>>>(cnt, excl, blockSums, N);
    scan_block_sums<<<1, L2_BLOCK, 0, stream>>>(blockSums, nb);
    add_offsets<<<nb, SCAN_BLOCK, 0, stream>>>(excl, blockSums, cursor, N);

    bucket_kernel<<<gridB, 256, 0, stream>>>(node_ids, cursor, perm, B);

    // Gather: 4 waves per 256-thread block, one wave per node.
    int gridG = (N + 3) / 4;
    gather_kernel<<<gridG, 256, 0, stream>>>(perm, excl, cnt, messages, timestamps,
                                             mean, last_ts, counts, N, D);
}